// Round 10
// baseline (155.507 us; speedup 1.0000x reference)
//
#include <hip/hip_runtime.h>

#define Bb 2
#define Ll 1024
#define Dd 256
#define Ee 64
#define Tt 8

typedef float f4 __attribute__((ext_vector_type(4)));

// K1: fold output projection into per-type transforms, stored TRANSPOSED:
// M1t[t][d][e] = sum_m W[e][m] * LT[t][m][d];  M2t likewise with RT, W[:,256:].
__global__ __launch_bounds__(128) void combine_kernel(const float* __restrict__ LT,
                                                      const float* __restrict__ RT,
                                                      const float* __restrict__ W,
                                                      float* __restrict__ M1t,
                                                      float* __restrict__ M2t) {
    int t  = blockIdx.x >> 5;
    int e0 = (blockIdx.x & 31) * 2;
    int tid = threadIdx.x;
    int ec = tid >> 6;
    int d4 = tid & 63;

    __shared__ float s_w1[2][Dd];
    __shared__ float s_w2[2][Dd];
    {
        const f4* w4 = (const f4*)(W + e0 * 2 * Dd);
        #pragma unroll
        for (int k = 0; k < 2; ++k) {
            int idx = tid + k * 128;
            f4 v = w4[idx];
            int row = idx >> 7;
            int c   = idx & 127;
            if (c < 64) *((f4*)&s_w1[row][0] + c)        = v;
            else        *((f4*)&s_w2[row][0] + (c - 64)) = v;
        }
    }
    __syncthreads();

    const f4* lt4 = (const f4*)(LT + t * Dd * Dd) + d4;
    const f4* rt4 = (const f4*)(RT + t * Dd * Dd) + d4;
    f4 a1 = {0.f, 0.f, 0.f, 0.f}, a2 = {0.f, 0.f, 0.f, 0.f};
    #pragma unroll 8
    for (int m = 0; m < Dd; ++m) {
        f4 lv = lt4[m * 64];
        f4 rv = rt4[m * 64];
        a1 += s_w1[ec][m] * lv;
        a2 += s_w2[ec][m] * rv;
    }
    int e = e0 + ec;
    #pragma unroll
    for (int j = 0; j < 4; ++j) {
        M1t[(t * Dd + d4 * 4 + j) * Ee + e] = a1[j];
        M2t[(t * Dd + d4 * 4 + j) * Ee + e] = a2[j];
    }
}

// K2: lp[b][l][e] = sum_d M1t[t][d][e]*emb[b][l][d], rp likewise. t=types[b][l].
__global__ __launch_bounds__(256) void proj_kernel(const float* __restrict__ emb,
                                                   const int* __restrict__ types,
                                                   const float* __restrict__ M1t,
                                                   const float* __restrict__ M2t,
                                                   float* __restrict__ lp,
                                                   float* __restrict__ rp) {
    int bl = blockIdx.x;
    int tid = threadIdx.x;
    __shared__ float s_e[Dd];
    s_e[tid] = emb[bl * Dd + tid];
    __syncthreads();
    int t = types[bl];
    int e = tid & 63;
    int chunk = tid >> 6;
    const float* m1 = M1t + (size_t)t * Dd * Ee + e;
    const float* m2 = M2t + (size_t)t * Dd * Ee + e;
    float a1 = 0.f, a2 = 0.f;
    #pragma unroll 8
    for (int dd = 0; dd < 64; ++dd) {
        int d = chunk * 64 + dd;
        float s = s_e[d];
        a1 = fmaf(m1[d * Ee], s, a1);
        a2 = fmaf(m2[d * Ee], s, a2);
    }
    __shared__ float r1[256], r2[256];
    r1[tid] = a1;
    r2[tid] = a2;
    __syncthreads();
    if (tid < 64) {
        lp[bl * Ee + tid] = r1[tid] + r1[tid + 64] + r1[tid + 128] + r1[tid + 192];
        rp[bl * Ee + tid] = r2[tid] + r2[tid + 64] + r2[tid + 128] + r2[tid + 192];
    }
}

// K3: out[b][l][m][e] = lp[b][l][e] + rp[b][m][e] + bias[e]
// ZERO-GLOBAL-DEP store loop (r8's bcast) with PLAIN stores — the untested
// {plain, zero-dep} cell. rp chunk in 16 VGPRs, lp+bias staged in 8KB LDS.
// Per row-iter the block writes a contiguous 16KB line; 8KB LDS + 24 VGPR
// -> ~6 blocks/CU (24 waves). Fill kernel proves plain zero-dep streams
// hit 6.6 TB/s; nt measured 4.5 (r8 probe).
__global__ __launch_bounds__(256) void bcast_kernel(const float* __restrict__ lp,
                                                    const float* __restrict__ rp,
                                                    const float* __restrict__ bias,
                                                    f4* __restrict__ out) {
    int blk = blockIdx.x;
    int lr = blk & 31;             // 32 l-ranges of 32 l
    int mc = (blk >> 5) & 15;      // 16 m-chunks of 64 m
    int b  = blk >> 9;
    int tid = threadIdx.x;
    int e4 = tid & 15;
    int ml = tid >> 4;
    int l0 = lr * 32;

    __shared__ f4 s_lp[512];       // 32 l-rows x 16 f4, bias folded in
    const f4* lp4 = (const f4*)lp;
    const f4* b4  = (const f4*)bias;
    size_t lbase = ((size_t)b * Ll + l0) * 16;
    #pragma unroll
    for (int i = 0; i < 2; ++i) {
        int idx = tid + i * 256;
        s_lp[idx] = lp4[lbase + idx] + b4[idx & 15];
    }

    const f4* rp4 = (const f4*)rp;
    f4 rv[4];
    #pragma unroll
    for (int k = 0; k < 4; ++k) {
        int m = mc * 64 + k * 16 + ml;
        rv[k] = rp4[((size_t)b * Ll + m) * 16 + e4];
    }
    __syncthreads();

    #pragma unroll 4
    for (int li = 0; li < 32; ++li) {
        f4 lv = s_lp[li * 16 + e4];   // LDS broadcast (free)
        f4* o = out + (((size_t)b * Ll + l0 + li) * Ll + mc * 64) * 16;
        #pragma unroll
        for (int k = 0; k < 4; ++k)
            o[(k * 16 + ml) * 16 + e4] = lv + rv[k];   // PLAIN store (A/B vs r8-nt)
    }
}

extern "C" void kernel_launch(void* const* d_in, const int* in_sizes, int n_in,
                              void* d_out, int out_size, void* d_ws, size_t ws_size,
                              hipStream_t stream) {
    const float* emb   = (const float*)d_in[0];
    const int*   types = (const int*)d_in[1];
    const float* LT    = (const float*)d_in[2];
    const float* RT    = (const float*)d_in[3];
    const float* W     = (const float*)d_in[4];
    const float* bias  = (const float*)d_in[5];

    float* ws = (float*)d_ws;
    float* M1t = ws;
    float* M2t = M1t + Tt * Dd * Ee;
    float* lp  = M2t + Tt * Dd * Ee;
    float* rp  = lp + Bb * Ll * Ee;

    combine_kernel<<<Tt * 32, 128, 0, stream>>>(LT, RT, W, M1t, M2t);
    proj_kernel<<<Bb * Ll, 256, 0, stream>>>(emb, types, M1t, M2t, lp, rp);
    bcast_kernel<<<Bb * 16 * 32, 256, 0, stream>>>(lp, rp, bias, (f4*)d_out);
}

// Round 11
// 122.693 us; speedup vs baseline: 1.2674x; 1.2674x over previous
//
#include <hip/hip_runtime.h>

#define Bb 2
#define Ll 1024
#define Dd 256
#define Ee 64
#define Tt 8

typedef float f4 __attribute__((ext_vector_type(4)));

// K1: fold output projection into per-type transforms, stored TRANSPOSED:
// M1t[t][d][e] = sum_m W[e][m] * LT[t][m][d];  M2t likewise with RT, W[:,256:].
__global__ __launch_bounds__(128) void combine_kernel(const float* __restrict__ LT,
                                                      const float* __restrict__ RT,
                                                      const float* __restrict__ W,
                                                      float* __restrict__ M1t,
                                                      float* __restrict__ M2t) {
    int t  = blockIdx.x >> 5;
    int e0 = (blockIdx.x & 31) * 2;
    int tid = threadIdx.x;
    int ec = tid >> 6;
    int d4 = tid & 63;

    __shared__ float s_w1[2][Dd];
    __shared__ float s_w2[2][Dd];
    {
        const f4* w4 = (const f4*)(W + e0 * 2 * Dd);
        #pragma unroll
        for (int k = 0; k < 2; ++k) {
            int idx = tid + k * 128;
            f4 v = w4[idx];
            int row = idx >> 7;
            int c   = idx & 127;
            if (c < 64) *((f4*)&s_w1[row][0] + c)        = v;
            else        *((f4*)&s_w2[row][0] + (c - 64)) = v;
        }
    }
    __syncthreads();

    const f4* lt4 = (const f4*)(LT + t * Dd * Dd) + d4;
    const f4* rt4 = (const f4*)(RT + t * Dd * Dd) + d4;
    f4 a1 = {0.f, 0.f, 0.f, 0.f}, a2 = {0.f, 0.f, 0.f, 0.f};
    #pragma unroll 8
    for (int m = 0; m < Dd; ++m) {
        f4 lv = lt4[m * 64];
        f4 rv = rt4[m * 64];
        a1 += s_w1[ec][m] * lv;
        a2 += s_w2[ec][m] * rv;
    }
    int e = e0 + ec;
    #pragma unroll
    for (int j = 0; j < 4; ++j) {
        M1t[(t * Dd + d4 * 4 + j) * Ee + e] = a1[j];
        M2t[(t * Dd + d4 * 4 + j) * Ee + e] = a2[j];
    }
}

// K2: lp[b][l][e] = sum_d M1t[t][d][e]*emb[b][l][d], rp likewise. t=types[b][l].
__global__ __launch_bounds__(256) void proj_kernel(const float* __restrict__ emb,
                                                   const int* __restrict__ types,
                                                   const float* __restrict__ M1t,
                                                   const float* __restrict__ M2t,
                                                   float* __restrict__ lp,
                                                   float* __restrict__ rp) {
    int bl = blockIdx.x;
    int tid = threadIdx.x;
    __shared__ float s_e[Dd];
    s_e[tid] = emb[bl * Dd + tid];
    __syncthreads();
    int t = types[bl];
    int e = tid & 63;
    int chunk = tid >> 6;
    const float* m1 = M1t + (size_t)t * Dd * Ee + e;
    const float* m2 = M2t + (size_t)t * Dd * Ee + e;
    float a1 = 0.f, a2 = 0.f;
    #pragma unroll 8
    for (int dd = 0; dd < 64; ++dd) {
        int d = chunk * 64 + dd;
        float s = s_e[d];
        a1 = fmaf(m1[d * Ee], s, a1);
        a2 = fmaf(m2[d * Ee], s, a2);
    }
    __shared__ float r1[256], r2[256];
    r1[tid] = a1;
    r2[tid] = a2;
    __syncthreads();
    if (tid < 64) {
        lp[bl * Ee + tid] = r1[tid] + r1[tid + 64] + r1[tid + 128] + r1[tid + 192];
        rp[bl * Ee + tid] = r2[tid] + r2[tid + 64] + r2[tid + 128] + r2[tid + 192];
    }
}

// K3: out[b][l][m][e] = lp[b][l][e] + rp[b][m][e] + bias[e]
// Zero-global-dep store loop (r10 shape). DUAL-PATH stores: k=0,1 go
// NONTEMPORAL (L2-bypass path, caps ~4.5 TB/s alone — r8 probe), k=2,3 go
// PLAIN (L2 write-combine path, caps ~4.2 alone). If the two caps are in
// different hardware queues, interleaving 8KB+8KB per 16KB row should sum.
__global__ __launch_bounds__(256) void bcast_kernel(const float* __restrict__ lp,
                                                    const float* __restrict__ rp,
                                                    const float* __restrict__ bias,
                                                    f4* __restrict__ out) {
    int blk = blockIdx.x;
    int lr = blk & 31;             // 32 l-ranges of 32 l
    int mc = (blk >> 5) & 15;      // 16 m-chunks of 64 m
    int b  = blk >> 9;
    int tid = threadIdx.x;
    int e4 = tid & 15;
    int ml = tid >> 4;
    int l0 = lr * 32;

    __shared__ f4 s_lp[512];       // 32 l-rows x 16 f4, bias folded in
    const f4* lp4 = (const f4*)lp;
    const f4* b4  = (const f4*)bias;
    size_t lbase = ((size_t)b * Ll + l0) * 16;
    #pragma unroll
    for (int i = 0; i < 2; ++i) {
        int idx = tid + i * 256;
        s_lp[idx] = lp4[lbase + idx] + b4[idx & 15];
    }

    const f4* rp4 = (const f4*)rp;
    f4 rv[4];
    #pragma unroll
    for (int k = 0; k < 4; ++k) {
        int m = mc * 64 + k * 16 + ml;
        rv[k] = rp4[((size_t)b * Ll + m) * 16 + e4];
    }
    __syncthreads();

    #pragma unroll 4
    for (int li = 0; li < 32; ++li) {
        f4 lv = s_lp[li * 16 + e4];   // LDS broadcast (free)
        f4* o = out + (((size_t)b * Ll + l0 + li) * Ll + mc * 64) * 16;
        // first 8KB of the row via nt (L2-bypass), second 8KB via plain (L2)
        __builtin_nontemporal_store(lv + rv[0], &o[(0 * 16 + ml) * 16 + e4]);
        __builtin_nontemporal_store(lv + rv[1], &o[(1 * 16 + ml) * 16 + e4]);
        o[(2 * 16 + ml) * 16 + e4] = lv + rv[2];
        o[(3 * 16 + ml) * 16 + e4] = lv + rv[3];
    }
}

extern "C" void kernel_launch(void* const* d_in, const int* in_sizes, int n_in,
                              void* d_out, int out_size, void* d_ws, size_t ws_size,
                              hipStream_t stream) {
    const float* emb   = (const float*)d_in[0];
    const int*   types = (const int*)d_in[1];
    const float* LT    = (const float*)d_in[2];
    const float* RT    = (const float*)d_in[3];
    const float* W     = (const float*)d_in[4];
    const float* bias  = (const float*)d_in[5];

    float* ws = (float*)d_ws;
    float* M1t = ws;
    float* M2t = M1t + Tt * Dd * Ee;
    float* lp  = M2t + Tt * Dd * Ee;
    float* rp  = lp + Bb * Ll * Ee;

    combine_kernel<<<Tt * 32, 128, 0, stream>>>(LT, RT, W, M1t, M2t);
    proj_kernel<<<Bb * Ll, 256, 0, stream>>>(emb, types, M1t, M2t, lp, rp);
    bcast_kernel<<<Bb * 16 * 32, 256, 0, stream>>>(lp, rp, bias, (f4*)d_out);
}